// Round 7
// baseline (949.909 us; speedup 1.0000x reference)
//
#include <hip/hip_runtime.h>

#define N_NODES 50000
#define E_EDGES 1600000
#define E2 (E_EDGES + N_NODES)   // 1,650,000 with self loops
#define HEADS 4
#define F 256
#define OUTC 10
#define BN_EPS 1e-5f
#define NEG_SLOPE 0.2f
#define SB 1024                  // scan block size
#define NB ((N_NODES + SB - 1) / SB)   // 49 scan blocks

static_assert(N_NODES % 4 == 0, "grid_nw exact");

typedef __attribute__((ext_vector_type(8))) short short8;
typedef __attribute__((ext_vector_type(8))) unsigned short ushort8v;
typedef __attribute__((ext_vector_type(4))) float f32x4;

__device__ __forceinline__ unsigned short f2bf(float f) {
    unsigned int u = __float_as_uint(f);
    unsigned int r = (u + 0x7fffu + ((u >> 16) & 1u)) >> 16;
    return (unsigned short)r;
}
__device__ __forceinline__ float bf2f(unsigned short b) {
    return __uint_as_float(((unsigned int)b) << 16);
}

// ---------------- convert X f32 -> bf16 ----------------
__global__ __launch_bounds__(256) void convert_x(
    const float* __restrict__ X, unsigned short* __restrict__ Xb)
{
    int i = blockIdx.x * blockDim.x + threadIdx.x;
    const int total = N_NODES * 128 / 4;
    if (i >= total) return;
    float4 v = reinterpret_cast<const float4*>(X)[i];
    ushort4 o = { f2bf(v.x), f2bf(v.y), f2bf(v.z), f2bf(v.w) };
    reinterpret_cast<ushort4*>(Xb)[i] = o;
}

// ---------------- convert W1 [128,256] f32 -> WT1b [256,128] bf16 ------
__global__ __launch_bounds__(256) void convert_w1T(
    const float* __restrict__ W1, unsigned short* __restrict__ WT)
{
    const int k = blockIdx.x;        // 128 blocks
    const int n = threadIdx.x;       // 256 threads, coalesced read
    WT[n * 128 + k] = f2bf(W1[k * 256 + n]);
}

// ---------------- CSR build (integer atomics only) ----------------
__global__ __launch_bounds__(256) void count_deg(
    const int* __restrict__ eidx, int* __restrict__ deg)
{
    int e = blockIdx.x * blockDim.x + threadIdx.x;
    if (e >= E2) return;
    int dst = (e < E_EDGES) ? eidx[E_EDGES + e] : e - E_EDGES;
    atomicAdd(&deg[dst], 1);
}

__global__ __launch_bounds__(SB) void scan_blocks(
    const int* __restrict__ deg, int* __restrict__ rowptr, int* __restrict__ bsum)
{
    __shared__ int sm[SB];
    const int t = threadIdx.x;
    const int idx = blockIdx.x * SB + t;
    int v = (idx < N_NODES) ? deg[idx] : 0;
    sm[t] = v;
    __syncthreads();
    for (int off = 1; off < SB; off <<= 1) {
        int u = (t >= off) ? sm[t - off] : 0;
        __syncthreads();
        sm[t] += u;
        __syncthreads();
    }
    if (idx < N_NODES) rowptr[idx] = sm[t] - v;
    if (t == SB - 1) bsum[blockIdx.x] = sm[t];
}

__global__ __launch_bounds__(64) void scan_bsums(
    const int* __restrict__ bsum, int* __restrict__ boff, int* __restrict__ rowptr)
{
    if (threadIdx.x == 0) {
        int run = 0;
        for (int b = 0; b < NB; b++) { boff[b] = run; run += bsum[b]; }
        rowptr[N_NODES] = run;
    }
}

__global__ __launch_bounds__(SB) void scan_add(
    int* __restrict__ rowptr, const int* __restrict__ boff)
{
    const int idx = blockIdx.x * SB + threadIdx.x;
    if (idx < N_NODES) rowptr[idx] += boff[blockIdx.x];
}

__global__ __launch_bounds__(256) void scatter_edges(
    const int* __restrict__ eidx, const int* __restrict__ rowptr,
    int* __restrict__ cursor, int* __restrict__ esrc)
{
    int e = blockIdx.x * blockDim.x + threadIdx.x;
    if (e >= E2) return;
    int src, dst;
    if (e < E_EDGES) { src = eidx[e]; dst = eidx[E_EDGES + e]; }
    else             { src = dst = e - E_EDGES; }
    int pos = atomicAdd(&cursor[dst], 1);
    esrc[rowptr[dst] + pos] = src;
}

// ------- MFMA GEMM + fused S/D: C = A@BT^T (+brow); S/D from f32 acc ---
template<int K, bool BROW>
__global__ __launch_bounds__(256) void gemm_sd(
    const unsigned short* __restrict__ A, const unsigned short* __restrict__ BT,
    const float* __restrict__ brow, const float* __restrict__ a_src,
    const float* __restrict__ a_dst, unsigned short* __restrict__ C,
    float* __restrict__ S, float* __restrict__ D)
{
    const int t = threadIdx.x;
    const int wave = t >> 6, lane = t & 63;      // wave == head
    const int lo = lane & 15, hi = lane >> 4;
    const int row0 = blockIdx.x * 64;
    const int nbase = wave * 64;

    int arow[4];
#pragma unroll
    for (int m = 0; m < 4; m++)
        arow[m] = min(row0 + m * 16 + lo, N_NODES - 1);   // never read unwritten ws

    f32x4 acc[4][4];
#pragma unroll
    for (int m = 0; m < 4; m++)
#pragma unroll
        for (int n = 0; n < 4; n++)
            acc[m][n] = (f32x4){0.f, 0.f, 0.f, 0.f};

    for (int k0 = 0; k0 < K; k0 += 32) {
        const int kk = k0 + hi * 8;
        short8 af[4], bfr[4];
#pragma unroll
        for (int m = 0; m < 4; m++)
            af[m] = *reinterpret_cast<const short8*>(A + (size_t)arow[m] * K + kk);
#pragma unroll
        for (int n = 0; n < 4; n++)
            bfr[n] = *reinterpret_cast<const short8*>(BT + (size_t)(nbase + n * 16 + lo) * K + kk);
#pragma unroll
        for (int m = 0; m < 4; m++)
#pragma unroll
            for (int n = 0; n < 4; n++)
                acc[m][n] = __builtin_amdgcn_mfma_f32_16x16x32_bf16(
                    af[m], bfr[n], acc[m][n], 0, 0, 0);
    }

    float bb[4], asv[4], adv[4];
#pragma unroll
    for (int n = 0; n < 4; n++) {
        int col = nbase + n * 16 + lo;
        bb[n]  = BROW ? brow[col] : 0.f;
        asv[n] = a_src[col];
        adv[n] = a_dst[col];
    }

#pragma unroll
    for (int m = 0; m < 4; m++) {
#pragma unroll
        for (int i = 0; i < 4; i++) {
            const int row = row0 + m * 16 + hi * 4 + i;
            const bool ok = row < N_NODES;
            float ps = 0.f, pd = 0.f;
#pragma unroll
            for (int n = 0; n < 4; n++) {
                float v = acc[m][n][i] + bb[n];
                ps += v * asv[n];
                pd += v * adv[n];
                if (ok) C[(size_t)row * F + nbase + n * 16 + lo] = f2bf(v);
            }
#pragma unroll
            for (int off = 1; off < 16; off <<= 1) {
                ps += __shfl_xor(ps, off, 64);
                pd += __shfl_xor(pd, off, 64);
            }
            if (lo == 0 && ok) {
                S[row * HEADS + wave] = ps;
                D[row * HEADS + wave] = pd;
            }
        }
    }
}

// ------- fused softmax + aggregation + bias + ReLU + batch stats -------
// Pair-gather: lanes 0-31 take edge j (16B = 8 channels each), lanes
// 32-63 edge j+1; halves combined by shfl_xor(32). Pad lanes write w4=0,
// src=0 (row 0 always valid) so pads contribute exactly zero.
__global__ __launch_bounds__(256) void gat_aggregate(
    const int* __restrict__ rowptr, const int* __restrict__ esrc,
    const float* __restrict__ S, const float* __restrict__ D,
    const unsigned short* __restrict__ XWb, const float* __restrict__ bias,
    unsigned short* __restrict__ Hb, float* __restrict__ st)
{
    __shared__ int   sbuf[4][64];
    __shared__ float wbuf[4][64][4];
    __shared__ float red_s[4][F];
    __shared__ float red_q[4][F];
    const int wv   = threadIdx.x >> 6;
    const int lane = threadIdx.x & 63;
    const int dst  = blockIdx.x * 4 + wv;        // always < N_NODES (N%4==0)
    const int beg = rowptr[dst], end = rowptr[dst + 1];
    const int half = lane >> 5;                  // 0: even edges, 1: odd
    const int hl   = lane & 31;                  // channel-group owner
    const int h    = hl >> 3;                    // head of my 8 channels
    const float4 d4 = *reinterpret_cast<const float4*>(D + dst * HEADS);

    float acc8[8];
#pragma unroll
    for (int k = 0; k < 8; k++) acc8[k] = 0.f;
    float den = 0.f;

    for (int i = beg; i < end; i += 64) {
        const int nb = min(64, end - i);
        const bool valid = (i + lane < end);
        const int mysrc = valid ? esrc[i + lane] : 0;
        float4 w4 = {0.f, 0.f, 0.f, 0.f};
        if (valid) {
            const float4 s4 = *reinterpret_cast<const float4*>(S + mysrc * HEADS);
            float z;
            z = s4.x + d4.x; w4.x = __expf(z > 0.f ? z : NEG_SLOPE * z);
            z = s4.y + d4.y; w4.y = __expf(z > 0.f ? z : NEG_SLOPE * z);
            z = s4.z + d4.z; w4.z = __expf(z > 0.f ? z : NEG_SLOPE * z);
            z = s4.w + d4.w; w4.w = __expf(z > 0.f ? z : NEG_SLOPE * z);
        }
        sbuf[wv][lane] = mysrc;
        *reinterpret_cast<float4*>(&wbuf[wv][lane][0]) = w4;

        const int jmax = (nb + 1) & ~1;
        int j = 0;
        for (; j + 7 < jmax; j += 8) {
            const int e0 = j + half, e1 = j + 2 + half, e2 = j + 4 + half, e3 = j + 6 + half;
            const int s0 = sbuf[wv][e0], s1 = sbuf[wv][e1];
            const int s2 = sbuf[wv][e2], s3 = sbuf[wv][e3];
            const float w0 = wbuf[wv][e0][h], w1 = wbuf[wv][e1][h];
            const float w2 = wbuf[wv][e2][h], w3 = wbuf[wv][e3][h];
            ushort8v x0 = *reinterpret_cast<const ushort8v*>(XWb + (size_t)s0 * F + hl * 8);
            ushort8v x1 = *reinterpret_cast<const ushort8v*>(XWb + (size_t)s1 * F + hl * 8);
            ushort8v x2 = *reinterpret_cast<const ushort8v*>(XWb + (size_t)s2 * F + hl * 8);
            ushort8v x3 = *reinterpret_cast<const ushort8v*>(XWb + (size_t)s3 * F + hl * 8);
#pragma unroll
            for (int k = 0; k < 8; k++)
                acc8[k] += w0 * bf2f(x0[k]) + w1 * bf2f(x1[k])
                         + w2 * bf2f(x2[k]) + w3 * bf2f(x3[k]);
            den += (w0 + w1) + (w2 + w3);
        }
        for (; j < jmax; j += 2) {
            const int e = j + half;
            const int s = sbuf[wv][e];
            const float w = wbuf[wv][e][h];
            ushort8v xv = *reinterpret_cast<const ushort8v*>(XWb + (size_t)s * F + hl * 8);
#pragma unroll
            for (int k = 0; k < 8; k++)
                acc8[k] += w * bf2f(xv[k]);
            den += w;
        }
    }

    // combine halves
    den += __shfl_xor(den, 32, 64);
#pragma unroll
    for (int k = 0; k < 8; k++)
        acc8[k] += __shfl_xor(acc8[k], 32, 64);

    const float inv = 1.f / (den + 1e-16f);
    if (half == 0) {
        float4 b0 = *reinterpret_cast<const float4*>(bias + hl * 8);
        float4 b1 = *reinterpret_cast<const float4*>(bias + hl * 8 + 4);
        float bb[8] = {b0.x, b0.y, b0.z, b0.w, b1.x, b1.y, b1.z, b1.w};
        ushort8v o;
#pragma unroll
        for (int k = 0; k < 8; k++) {
            float v = acc8[k] * inv + bb[k];
            v = v > 0.f ? v : 0.f;
            o[k] = (short)f2bf(v);
            red_s[wv][hl * 8 + k] = v;
            red_q[wv][hl * 8 + k] = v * v;
        }
        *reinterpret_cast<ushort8v*>(Hb + (size_t)dst * F + hl * 8) = o;
    }
    __syncthreads();
    // block-level stats -> global atomics (f32; ULP-order jitter only)
    const int ch = threadIdx.x;
    float s = red_s[0][ch] + red_s[1][ch] + red_s[2][ch] + red_s[3][ch];
    float q = red_q[0][ch] + red_q[1][ch] + red_q[2][ch] + red_q[3][ch];
    atomicAdd(&st[ch], s);
    atomicAdd(&st[F + ch], q);
}

// ---------------- BN prep + brow (layer 1 -> layer 2 fold), 1 block ----
__global__ __launch_bounds__(256) void prep_brow(
    const float* __restrict__ st, const float* __restrict__ g,
    const float* __restrict__ be, const float* __restrict__ W2,
    float* __restrict__ scb, float* __restrict__ shb, float* __restrict__ brow)
{
    __shared__ float sh_l[F];
    const int t = threadIdx.x;
    const float inv_n = 1.f / (float)N_NODES;
    float mu = st[t] * inv_n;
    float var = st[F + t] * inv_n - mu * mu;
    float sc = rsqrtf(var + BN_EPS) * g[t];
    float sh = be[t] - mu * sc;
    scb[t] = sc;
    shb[t] = sh;
    sh_l[t] = sh;
    __syncthreads();
    float acc = 0.f;
    for (int k = 0; k < F; k++)
        acc += sh_l[k] * W2[(size_t)k * F + t];
    brow[t] = acc;
}

// ---------------- fold BN1 into W2 (transposed bf16) ----------------
__global__ __launch_bounds__(256) void fold_w2(
    const float* __restrict__ W2, const float* __restrict__ scb,
    unsigned short* __restrict__ WT2b)
{
    const int t = threadIdx.x;       // n
    const int k0 = blockIdx.x * 8;
#pragma unroll
    for (int kk = 0; kk < 8; kk++)
        WT2b[(size_t)t * F + k0 + kk] = f2bf(W2[(size_t)(k0 + kk) * F + t] * scb[k0 + kk]);
}

// ---------------- BN2 prep + fold into classifier weights, 1 block ----
__global__ __launch_bounds__(256) void fold_wc(
    const float* __restrict__ st, const float* __restrict__ g,
    const float* __restrict__ be, const float* __restrict__ Wc,
    const float* __restrict__ bc, float* __restrict__ Wcp, float* __restrict__ bcp)
{
    __shared__ float sc_l[F], sh_l[F];
    const int t = threadIdx.x;
    const float inv_n = 1.f / (float)N_NODES;
    float mu = st[t] * inv_n;
    float var = st[F + t] * inv_n - mu * mu;
    float sc = rsqrtf(var + BN_EPS) * g[t];
    sc_l[t] = sc;
    sh_l[t] = be[t] - mu * sc;
    __syncthreads();
#pragma unroll
    for (int o = 0; o < OUTC; o++)
        Wcp[t * OUTC + o] = Wc[t * OUTC + o] * sc_l[t];
    if (t < OUTC) {
        float acc = bc[t];
        for (int kk = 0; kk < F; kk++)
            acc += sh_l[kk] * Wc[kk * OUTC + t];
        bcp[t] = acc;
    }
}

// ---------------- classifier: [N,256]bf16 @ Wcp[256,10] + bcp --------
__global__ __launch_bounds__(256) void classifier(
    const unsigned short* __restrict__ Hb, const float* __restrict__ Wcp,
    const float* __restrict__ bcp, float* __restrict__ out)
{
    __shared__ float wls[F][OUTC + 1];
    const int t = threadIdx.x;
    for (int i = t; i < F * OUTC; i += 256)
        wls[i / OUTC][i % OUTC] = Wcp[i];
    __syncthreads();

    const int wave = t >> 6, lane = t & 63;
    const int n = blockIdx.x * 4 + wave;
    if (n >= N_NODES) return;

    float v[4];
#pragma unroll
    for (int j = 0; j < 4; j++)
        v[j] = bf2f(Hb[(size_t)n * F + j * 64 + lane]);

    float acc[OUTC];
#pragma unroll
    for (int o = 0; o < OUTC; o++) acc[o] = 0.f;
#pragma unroll
    for (int j = 0; j < 4; j++)
#pragma unroll
        for (int o = 0; o < OUTC; o++)
            acc[o] += v[j] * wls[j * 64 + lane][o];

#pragma unroll
    for (int off = 32; off > 0; off >>= 1)
#pragma unroll
        for (int o = 0; o < OUTC; o++)
            acc[o] += __shfl_xor(acc[o], off, 64);

    if (lane == 0) {
#pragma unroll
        for (int o = 0; o < OUTC; o++)
            out[(size_t)n * OUTC + o] = acc[o] + bcp[o];
    }
}

extern "C" void kernel_launch(void* const* d_in, const int* in_sizes, int n_in,
                              void* d_out, int out_size, void* d_ws, size_t ws_size,
                              hipStream_t stream)
{
    const float* x   = (const float*)d_in[0];
    const int*   ei  = (const int*)d_in[1];
    const float* W1  = (const float*)d_in[2];
    const float* as1 = (const float*)d_in[3];
    const float* ad1 = (const float*)d_in[4];
    const float* b1  = (const float*)d_in[5];
    const float* W2  = (const float*)d_in[6];
    const float* as2 = (const float*)d_in[7];
    const float* ad2 = (const float*)d_in[8];
    const float* b2  = (const float*)d_in[9];
    const float* g1  = (const float*)d_in[10];
    const float* be1 = (const float*)d_in[11];
    const float* g2  = (const float*)d_in[12];
    const float* be2 = (const float*)d_in[13];
    const float* Wc  = (const float*)d_in[14];
    const float* bc  = (const float*)d_in[15];
    float* out = (float*)d_out;

    char* w = (char*)d_ws;
    unsigned short* Xb   = (unsigned short*)w;   w += (size_t)N_NODES * 128 * 2;
    unsigned short* XWb  = (unsigned short*)w;   w += (size_t)N_NODES * F * 2;
    unsigned short* Hb   = (unsigned short*)w;   w += (size_t)N_NODES * F * 2;
    unsigned short* WT1b = (unsigned short*)w;   w += 256 * 128 * 2;
    unsigned short* WT2b = (unsigned short*)w;   w += 256 * 256 * 2;
    float* Wcp   = (float*)w;                    w += F * OUTC * 4;
    float* bcp   = (float*)w;                    w += 64;
    float* brow2 = (float*)w;                    w += F * 4;
    float* scb   = (float*)w;                    w += F * 4;
    float* shb   = (float*)w;                    w += F * 4;
    float* Sv    = (float*)w;                    w += (size_t)N_NODES * HEADS * 4;
    float* Dv    = (float*)w;                    w += (size_t)N_NODES * HEADS * 4;
    float* st1   = (float*)w;                    w += 2 * F * 4;   // st1,st2 contiguous
    float* st2   = (float*)w;                    w += 2 * F * 4;
    int* deg     = (int*)w;                      w += (size_t)N_NODES * 4;  // deg,cursor contiguous
    int* cursor  = (int*)w;                      w += (size_t)N_NODES * 4;
    int* rowp    = (int*)w;                      w += (size_t)(N_NODES + 1) * 4;
    int* bsum    = (int*)w;                      w += NB * 4;
    int* boff    = (int*)w;                      w += NB * 4;
    int* esrc    = (int*)w;                      /* E2 ints */

    const int grid_e    = (E2 + 255) / 256;
    const int grid_nw   = N_NODES / 4;           // 12500, exact
    const int grid_gemm = (N_NODES + 63) / 64;   // 782

    // ---- prep ----
    hipMemsetAsync(deg, 0, (size_t)N_NODES * 2 * 4, stream);   // deg + cursor
    hipMemsetAsync(st1, 0, 4 * F * 4, stream);                 // st1 + st2
    convert_x<<<(N_NODES * 128 / 4 + 255) / 256, 256, 0, stream>>>(x, Xb);
    convert_w1T<<<128, 256, 0, stream>>>(W1, WT1b);
    count_deg<<<grid_e, 256, 0, stream>>>(ei, deg);
    scan_blocks<<<NB, SB, 0, stream>>>(deg, rowp, bsum);
    scan_bsums<<<1, 64, 0, stream>>>(bsum, boff, rowp);
    scan_add<<<NB, SB, 0, stream>>>(rowp, boff);
    scatter_edges<<<grid_e, 256, 0, stream>>>(ei, rowp, cursor, esrc);

    // ---- layer 1 ----
    gemm_sd<128, false><<<grid_gemm, 256, 0, stream>>>(
        Xb, WT1b, nullptr, as1, ad1, XWb, Sv, Dv);
    gat_aggregate<<<grid_nw, 256, 0, stream>>>(rowp, esrc, Sv, Dv, XWb, b1, Hb, st1);
    prep_brow<<<1, 256, 0, stream>>>(st1, g1, be1, W2, scb, shb, brow2);
    fold_w2<<<32, 256, 0, stream>>>(W2, scb, WT2b);

    // ---- layer 2 ----
    gemm_sd<256, true><<<grid_gemm, 256, 0, stream>>>(
        Hb, WT2b, brow2, as2, ad2, XWb, Sv, Dv);
    gat_aggregate<<<grid_nw, 256, 0, stream>>>(rowp, esrc, Sv, Dv, XWb, b2, Hb, st2);
    fold_wc<<<1, 256, 0, stream>>>(st2, g2, be2, Wc, bc, Wcp, bcp);

    // ---- classifier ----
    classifier<<<grid_nw, 256, 0, stream>>>(Hb, Wcp, bcp, out);
}